// Round 5
// baseline (250.939 us; speedup 1.0000x reference)
//
#include <hip/hip_runtime.h>

#define KNN 30
#define FDIM 64
#define HDIM 64

typedef short s8v __attribute__((ext_vector_type(8)));   // 8 bf16 bit-patterns (4 VGPR)
typedef float f4v __attribute__((ext_vector_type(4)));   // MFMA accumulator
typedef unsigned long long u64;

// round-to-nearest-even f32 -> bf16 bits
static __device__ __forceinline__ unsigned short f2bf(float f) {
  unsigned int u = __builtin_bit_cast(unsigned int, f);
  u += 0x7fffu + ((u >> 16) & 1u);
  return (unsigned short)(u >> 16);
}
static __device__ __forceinline__ float bf2f(unsigned short h) {
  unsigned int u = ((unsigned int)h) << 16;
  return __builtin_bit_cast(float, u);
}

// f32 bits -> order-preserving u32 (asc float order == asc uint order)
static __device__ __forceinline__ unsigned int f2sort(float f) {
  unsigned int u = __builtin_bit_cast(unsigned int, f);
  unsigned int m = (unsigned int)(((int)u) >> 31) | 0x80000000u;
  return u ^ m;
}

// XOR swizzle (ushort-index space): byte ^= (row&7)<<4  <=>  idx ^= (row&7)<<3
static __device__ __forceinline__ int swzi(int row, int col, int roww) {
  return (row * roww + col) ^ ((row & 7) << 3);
}

static __device__ __forceinline__ void lds_fence() {
  asm volatile("s_waitcnt lgkmcnt(0)" ::: "memory");
  __builtin_amdgcn_sched_barrier(0);
}

static __device__ __forceinline__ s8v pack8(float4 a, float4 b) {
  s8v v;
  v[0] = (short)f2bf(a.x); v[1] = (short)f2bf(a.y);
  v[2] = (short)f2bf(a.z); v[3] = (short)f2bf(a.w);
  v[4] = (short)f2bf(b.x); v[5] = (short)f2bf(b.y);
  v[6] = (short)f2bf(b.z); v[7] = (short)f2bf(b.w);
  return v;
}

// ---------------- sq[i] = |x_i|^2 ----------------
__global__ __launch_bounds__(256) void sq_kernel(const float* __restrict__ x,
                                                 float* __restrict__ sq) {
  int lane = threadIdx.x & 63;
  int row = blockIdx.x * 4 + (threadIdx.x >> 6);
  float v = x[(size_t)row * FDIM + lane];
  float s = v * v;
#pragma unroll
  for (int off = 32; off; off >>= 1) s += __shfl_xor(s, off);
  if (lane == 0) sq[row] = s;
}

// ---------------- U/P precompute (layer-1 algebraic elimination) ----------------
__global__ __launch_bounds__(256) void uP_kernel(const float* __restrict__ x,
                                                 const float* __restrict__ W1,
                                                 const float* __restrict__ b1,
                                                 float* __restrict__ U,
                                                 unsigned short* __restrict__ P) {
  __shared__ __align__(16) unsigned short sWT[128 * 64];
  int t = threadIdx.x;
  for (int e = t; e < 64 * 64; e += 256) {
    int f = e >> 6, h = e & 63;
    float wa = W1[f * 64 + h];
    float wb = W1[(64 + f) * 64 + h];
    sWT[swzi(h, f, 64)] = f2bf(wa + wb);
    sWT[swzi(64 + h, f, 64)] = f2bf(wb);
  }
  __syncthreads();
  int wv = t >> 6, lane = t & 63;
  int q = lane >> 4, cl = lane & 15;
  int base = blockIdx.x * 128 + wv * 32;

  s8v af[2][2];
#pragma unroll
  for (int mt = 0; mt < 2; ++mt)
#pragma unroll
    for (int ks = 0; ks < 2; ++ks) {
      const float* px = x + (size_t)(base + mt * 16 + cl) * FDIM + ks * 32 + q * 8;
      float4 a = *reinterpret_cast<const float4*>(px);
      float4 b = *reinterpret_cast<const float4*>(px + 4);
      af[mt][ks] = pack8(a, b);
    }
  f4v acc[2][8];
#pragma unroll
  for (int nt = 0; nt < 8; ++nt) {
    float bb = (nt < 4) ? b1[nt * 16 + cl] : 0.0f;
    f4v a0 = {bb, bb, bb, bb};
    acc[0][nt] = a0;
    acc[1][nt] = a0;
  }
#pragma unroll
  for (int ks = 0; ks < 2; ++ks)
#pragma unroll
    for (int nt = 0; nt < 8; ++nt) {
      s8v wf = *reinterpret_cast<const s8v*>(&sWT[swzi(nt * 16 + cl, ks * 32 + q * 8, 64)]);
      acc[0][nt] = __builtin_amdgcn_mfma_f32_16x16x32_bf16(af[0][ks], wf, acc[0][nt], 0, 0, 0);
      acc[1][nt] = __builtin_amdgcn_mfma_f32_16x16x32_bf16(af[1][ks], wf, acc[1][nt], 0, 0, 0);
    }
#pragma unroll
  for (int mt = 0; mt < 2; ++mt)
#pragma unroll
    for (int nt = 0; nt < 8; ++nt)
#pragma unroll
      for (int i = 0; i < 4; ++i) {
        int row = base + mt * 16 + q * 4 + i;
        if (nt < 4) U[(size_t)row * 64 + nt * 16 + cl] = acc[mt][nt][i];
        else        P[(size_t)row * 64 + (nt - 4) * 16 + cl] = f2bf(acc[mt][nt][i]);
      }
}

// ---------------- fused KNN: bf16-MFMA keys in LDS + approx-select + exact rescan ----
// Block = 512 threads (8 waves) owns 32 rows of one batch. Key strip [32][2048] u16
// lives entirely in LDS (128KB); no distance matrix ever touches global memory.
// key = clamp(round((sq[w] - 2*dot_bf16 + 256)*64)); margin +66 covers |bf16-fp32|<=0.5.
__global__ __launch_bounds__(512) void knn_kernel(const float* __restrict__ x,
                                                  const float* __restrict__ sq,
                                                  int* __restrict__ idxout, int V) {
  __shared__ __align__(16) unsigned short sKey[32 * 2048];  // 128KB key strip
  __shared__ __align__(16) unsigned short sA[32 * 64];      // 4KB A tile
  __shared__ __align__(16) char sBraw[16384];               // B tile; later pools
  unsigned short* sB = reinterpret_cast<unsigned short*>(sBraw);

  int t = threadIdx.x;
  int strips = V / 32;
  int b = blockIdx.x / strips;
  int s0 = (blockIdx.x % strips) * 32;  // batch-local first row of strip
  const float* xb = x + (size_t)b * V * FDIM;
  size_t bbase = (size_t)b * V;

  // stage A (32 rows x 64 feat -> bf16, swizzled)
  if (t < 128) {
    int r = t >> 2, c0 = (t & 3) * 16;
    const float* p = xb + (size_t)(s0 + r) * FDIM + c0;
    float4 a0 = *reinterpret_cast<const float4*>(p);
    float4 a1 = *reinterpret_cast<const float4*>(p + 4);
    float4 a2 = *reinterpret_cast<const float4*>(p + 8);
    float4 a3 = *reinterpret_cast<const float4*>(p + 12);
    *reinterpret_cast<s8v*>(&sA[swzi(r, c0, 64)]) = pack8(a0, a1);
    *reinterpret_cast<s8v*>(&sA[swzi(r, c0 + 8, 64)]) = pack8(a2, a3);
  }
  __syncthreads();

  int wv = t >> 6, lane = t & 63;
  int q = lane >> 4, cl = lane & 15;
  int rh = (wv & 1) * 16;   // row half of strip
  int cq = (wv >> 1) * 32;  // col quarter of tile

  s8v af[2];
#pragma unroll
  for (int ks = 0; ks < 2; ++ks)
    af[ks] = *reinterpret_cast<const s8v*>(&sA[swzi(rh + cl, ks * 32 + q * 8, 64)]);

  // 16 tiles of 128 cols: MFMA -> u16 keys into sKey
  for (int tt = 0; tt < 16; ++tt) {
    __syncthreads();  // previous tile's frag reads done; sB reusable
    {
      int r = t >> 2, c0 = (t & 3) * 16;
      const float* p = xb + (size_t)(tt * 128 + r) * FDIM + c0;
      float4 a0 = *reinterpret_cast<const float4*>(p);
      float4 a1 = *reinterpret_cast<const float4*>(p + 4);
      float4 a2 = *reinterpret_cast<const float4*>(p + 8);
      float4 a3 = *reinterpret_cast<const float4*>(p + 12);
      *reinterpret_cast<s8v*>(&sB[swzi(r, c0, 64)]) = pack8(a0, a1);
      *reinterpret_cast<s8v*>(&sB[swzi(r, c0 + 8, 64)]) = pack8(a2, a3);
    }
    __syncthreads();
    f4v acc[2];
#pragma unroll
    for (int nt = 0; nt < 2; ++nt) {
      f4v z = {0.0f, 0.0f, 0.0f, 0.0f};
      acc[nt] = z;
    }
#pragma unroll
    for (int ks = 0; ks < 2; ++ks)
#pragma unroll
      for (int nt = 0; nt < 2; ++nt) {
        s8v bf = *reinterpret_cast<const s8v*>(&sB[swzi(cq + nt * 16 + cl, ks * 32 + q * 8, 64)]);
        acc[nt] = __builtin_amdgcn_mfma_f32_16x16x32_bf16(af[ks], bf, acc[nt], 0, 0, 0);
      }
    float sqn[2];
#pragma unroll
    for (int nt = 0; nt < 2; ++nt) sqn[nt] = sq[bbase + tt * 128 + cq + nt * 16 + cl];
#pragma unroll
    for (int nt = 0; nt < 2; ++nt)
#pragma unroll
      for (int i = 0; i < 4; ++i) {
        int rr = rh + q * 4 + i;
        int col = tt * 128 + cq + nt * 16 + cl;
        float dk = fmaf(-128.0f, acc[nt][i], fmaf(64.0f, sqn[nt], 16384.0f));
        int ki = (int)(dk + 0.5f);
        ki = ki < 0 ? 0 : (ki > 65535 ? 65535 : ki);
        sKey[rr * 2048 + (col ^ ((rr & 7) << 3))] = (unsigned short)ki;
      }
  }
  __syncthreads();  // all keys visible to all waves

  // selection: wave wv handles rows wv*4 .. wv*4+3 sequentially (topk16 algorithm on LDS)
  unsigned int* pool = reinterpret_cast<unsigned int*>(sBraw) + wv * 128;
  u64* pool2 = reinterpret_cast<u64*>(sBraw + 4096) + wv * 128;

  for (int j4 = 0; j4 < 4; ++j4) {
    int rr = wv * 4 + j4;
    int R = b * V + s0 + rr;  // global row
    int sw = (rr & 7) << 3;

    unsigned int kv[32];
#pragma unroll
    for (int s = 0; s < 4; ++s) {
      s8v raw = *reinterpret_cast<const s8v*>(&sKey[rr * 2048 + s * 512 + lane * 8]);
      int cbase = (s * 512 + lane * 8) ^ sw;
#pragma unroll
      for (int jj = 0; jj < 8; ++jj)
        kv[s * 8 + jj] = ((unsigned int)(unsigned short)raw[jj] << 16) | (unsigned int)(cbase + jj);
    }
    unsigned int mn = kv[0];
#pragma unroll
    for (int r = 1; r < 32; ++r) mn = min(mn, kv[r]);

    // bitonic-64 of lane minima -> tau (rank 30) bounds true rank-31 from above
    unsigned int srt = mn;
#pragma unroll
    for (int k = 2; k <= 64; k <<= 1) {
#pragma unroll
      for (int j = k >> 1; j > 0; j >>= 1) {
        unsigned int o = __shfl_xor(srt, j);
        bool keep_min = ((lane & k) == 0) == ((lane & j) == 0);
        bool less = srt < o;
        srt = (keep_min == less) ? srt : o;
      }
    }
    unsigned int tauk = (__shfl(srt, 30) >> 16) + 66;

    // compact candidates (key16 <= tauk) into pool
    int base = 0;
#pragma unroll
    for (int r = 0; r < 32; ++r) {
      bool pred = (kv[r] >> 16) <= tauk;
      u64 m = __ballot(pred);
      unsigned int off = __builtin_amdgcn_mbcnt_lo((unsigned int)m, 0u);
      off = __builtin_amdgcn_mbcnt_hi((unsigned int)(m >> 32), off);
      int slot = base + (int)off;
      if (pred && slot < 128) pool[slot] = kv[r];
      base += (int)__popcll(m);
    }

    if (base <= 128) {
      lds_fence();
      // exact fp32 rescan: 8-lane groups, group g handles candidates it*8+g
      int g = lane >> 3, sub = lane & 7;
      const float* xvp = x + (size_t)R * FDIM + sub * 8;
      float4 xv0 = *reinterpret_cast<const float4*>(xvp);
      float4 xv1 = *reinterpret_cast<const float4*>(xvp + 4);
      float xv[8] = {xv0.x, xv0.y, xv0.z, xv0.w, xv1.x, xv1.y, xv1.z, xv1.w};
      int rounds = (base + 7) >> 3;
      for (int it = 0; it < rounds; ++it) {
        int c = it * 8 + g;
        unsigned int pk = pool[c < base ? c : 0];
        int w = (int)(pk & 0xFFFFu);
        const float* xwp = x + (bbase + (unsigned int)w) * FDIM + sub * 8;
        float4 b0 = *reinterpret_cast<const float4*>(xwp);
        float4 b1 = *reinterpret_cast<const float4*>(xwp + 4);
        float dot = xv[0] * b0.x;
        dot = fmaf(xv[1], b0.y, dot); dot = fmaf(xv[2], b0.z, dot);
        dot = fmaf(xv[3], b0.w, dot); dot = fmaf(xv[4], b1.x, dot);
        dot = fmaf(xv[5], b1.y, dot); dot = fmaf(xv[6], b1.z, dot);
        dot = fmaf(xv[7], b1.w, dot);
        dot += __shfl_xor(dot, 1);
        dot += __shfl_xor(dot, 2);
        dot += __shfl_xor(dot, 4);
        float dx = fmaf(-2.0f, dot, sq[bbase + (unsigned int)w]);
        if (sub == 0 && c < base)
          pool2[c] = ((u64)f2sort(dx) << 32) | (unsigned int)w;
      }
      lds_fence();
      u64 keyA = (lane < base) ? pool2[lane] : ~0ULL;
      if (base <= 64) {
#pragma unroll
        for (int k = 2; k <= 64; k <<= 1) {
#pragma unroll
          for (int j = k >> 1; j > 0; j >>= 1) {
            u64 o = __shfl_xor(keyA, j);
            bool keep_min = ((lane & k) == 0) == ((lane & j) == 0);
            bool less = keyA < o;
            keyA = (keep_min == less) ? keyA : o;
          }
        }
        if (lane >= 1 && lane <= KNN)
          idxout[(size_t)R * KNN + (lane - 1)] = (int)(unsigned int)(keyA & 0xFFFFFFFFu);
      } else {
        u64 keyB = (64 + lane < base) ? pool2[64 + lane] : ~0ULL;
#pragma unroll
        for (int k = 2; k <= 64; k <<= 1) {
#pragma unroll
          for (int j = k >> 1; j > 0; j >>= 1) {
            u64 oA = __shfl_xor(keyA, j);
            bool keep_min = ((lane & k) == 0) == ((lane & j) == 0);
            keyA = (keep_min == (keyA < oA)) ? keyA : oA;
            u64 oB = __shfl_xor(keyB, j);
            keyB = (keep_min == (keyB < oB)) ? keyB : oB;
          }
        }
        // merge: A asc + reverse(B asc) -> elementwise min is bitonic & holds smallest 64
        u64 keyBr = __shfl(keyB, 63 - lane);
        u64 mnk = keyA < keyBr ? keyA : keyBr;
#pragma unroll
        for (int j = 32; j > 0; j >>= 1) {
          u64 o = __shfl_xor(mnk, j);
          bool keep_min = (lane & j) == 0;
          mnk = (keep_min == (mnk < o)) ? mnk : o;
        }
        if (lane >= 1 && lane <= KNN)
          idxout[(size_t)R * KNN + (lane - 1)] = (int)(unsigned int)(mnk & 0xFFFFFFFFu);
      }
    } else {
      // exhaustive exact fallback (pathological clustering only)
      float* sXv = reinterpret_cast<float*>(pool2);
      sXv[lane] = x[(size_t)R * FDIM + lane];
      lds_fence();
      unsigned int sve[32];
#pragma unroll 1
      for (int r = 0; r < 32; ++r) {
        int w = r * 64 + lane;
        const float* xw = xb + (size_t)w * FDIM;
        float dot = 0.0f;
        for (int f = 0; f < 64; ++f) dot = fmaf(sXv[f], xw[f], dot);
        sve[r] = f2sort(fmaf(-2.0f, dot, sq[bbase + (unsigned int)w]));
      }
      unsigned int removed = 0;
      for (int it = 0; it < KNN + 1; ++it) {
        u64 m = ~0ULL;
#pragma unroll
        for (int r = 0; r < 32; ++r) {
          u64 key = ((u64)sve[r] << 32) | (unsigned int)(r * 64 + lane);
          bool alive = ((removed >> r) & 1u) == 0u;
          if (alive && key < m) m = key;
        }
        u64 gk = m;
#pragma unroll
        for (int off = 32; off; off >>= 1) {
          u64 o = __shfl_xor(gk, off);
          gk = (o < gk) ? o : gk;
        }
        if (it > 0 && lane == 0)
          idxout[(size_t)R * KNN + (it - 1)] = (int)(unsigned int)(gk & 0xFFFFFFFFu);
#pragma unroll
        for (int r = 0; r < 32; ++r) {
          u64 key = ((u64)sve[r] << 32) | (unsigned int)(r * 64 + lane);
          if (key == gk) removed |= (1u << r);
        }
      }
    }
  }
}

// ---------------- fused layers 2,3 + max aggregation ----------------
__global__ __launch_bounds__(256) void mlp_kernel(const float* __restrict__ U,
                                                  const unsigned short* __restrict__ P,
                                                  const int* __restrict__ idx,
                                                  const float* __restrict__ W2,
                                                  const float* __restrict__ b2,
                                                  const float* __restrict__ W3,
                                                  const float* __restrict__ b3,
                                                  float* __restrict__ out, int V) {
  __shared__ __align__(16) unsigned short sW2T[HDIM * HDIM];
  __shared__ __align__(16) unsigned short sW3T[HDIM * HDIM];
  __shared__ __align__(16) unsigned short sScr[4][2048];
  int t = threadIdx.x;
  for (int e = t; e < HDIM * HDIM; e += 256) {
    int i = e >> 6, j = e & 63;
    sW2T[swzi(j, i, 64)] = f2bf(W2[e]);
    int s = (i & 15) * 4 + (i >> 4);
    sW3T[swzi(j, s, 64)] = f2bf(W3[e]);
  }
  __syncthreads();

  int wv = t >> 6, lane = t & 63;
  int q = lane >> 4, cl = lane & 15;
  int g = lane >> 3, sub = lane & 7;
  unsigned short* scr = &sScr[wv][0];
  float bias2[4], bias3[4];
#pragma unroll
  for (int nt = 0; nt < 4; ++nt) {
    bias2[nt] = b2[nt * 16 + cl];
    bias3[nt] = b3[nt * 16 + cl];
  }

  for (int vi = 0; vi < 4; ++vi) {
    int v = blockIdx.x * 16 + wv * 4 + vi;
    int b = v / V;
    size_t bbase = (size_t)b * V;
    int myidx = (lane < KNN) ? idx[(size_t)v * KNN + lane] : 0;
    const float* up = U + (size_t)v * 64 + sub * 8;
    float4 u0 = *reinterpret_cast<const float4*>(up);
    float4 u1 = *reinterpret_cast<const float4*>(up + 4);
    float uu[8] = {u0.x, u0.y, u0.z, u0.w, u1.x, u1.y, u1.z, u1.w};

#pragma unroll
    for (int it = 0; it < 4; ++it) {
      int r = it * 8 + g;
      int kk = (r < KNN) ? r : (KNN - 1);
      int nb = __shfl(myidx, kk);
      const unsigned short* pp = P + (bbase + (unsigned int)nb) * 64 + sub * 8;
      s8v p8 = *reinterpret_cast<const s8v*>(pp);
      s8v hv;
#pragma unroll
      for (int j = 0; j < 8; ++j) {
        float f = uu[j] - bf2f((unsigned short)p8[j]);
        hv[j] = (short)f2bf(fmaxf(f, 0.0f));
      }
      *reinterpret_cast<s8v*>(&scr[swzi(r, sub * 8, 64)]) = hv;
    }
    lds_fence();

    s8v af2[2][2];
#pragma unroll
    for (int mt = 0; mt < 2; ++mt)
#pragma unroll
      for (int ks = 0; ks < 2; ++ks)
        af2[mt][ks] = *reinterpret_cast<const s8v*>(&scr[swzi(mt * 16 + cl, ks * 32 + q * 8, 64)]);
    f4v acc2[2][4];
#pragma unroll
    for (int mt = 0; mt < 2; ++mt)
#pragma unroll
      for (int nt = 0; nt < 4; ++nt) {
        f4v a0 = {bias2[nt], bias2[nt], bias2[nt], bias2[nt]};
        acc2[mt][nt] = a0;
      }
#pragma unroll
    for (int ks = 0; ks < 2; ++ks)
#pragma unroll
      for (int nt = 0; nt < 4; ++nt) {
        s8v wf = *reinterpret_cast<const s8v*>(&sW2T[swzi(nt * 16 + cl, ks * 32 + q * 8, 64)]);
        acc2[0][nt] = __builtin_amdgcn_mfma_f32_16x16x32_bf16(af2[0][ks], wf, acc2[0][nt], 0, 0, 0);
        acc2[1][nt] = __builtin_amdgcn_mfma_f32_16x16x32_bf16(af2[1][ks], wf, acc2[1][nt], 0, 0, 0);
      }
    lds_fence();
#pragma unroll
    for (int mt = 0; mt < 2; ++mt)
#pragma unroll
      for (int i = 0; i < 4; ++i) {
        int m = mt * 16 + q * 4 + i;
        u64 pk = 0;
#pragma unroll
        for (int nt = 0; nt < 4; ++nt) {
          u64 hb = f2bf(fmaxf(acc2[mt][nt][i], 0.0f));
          pk |= hb << (16 * nt);
        }
        *reinterpret_cast<u64*>(&scr[swzi(m, cl * 4, 64)]) = pk;
      }
    lds_fence();

    s8v af3[2][2];
#pragma unroll
    for (int mt = 0; mt < 2; ++mt)
#pragma unroll
      for (int ks = 0; ks < 2; ++ks)
        af3[mt][ks] = *reinterpret_cast<const s8v*>(&scr[swzi(mt * 16 + cl, ks * 32 + q * 8, 64)]);
    f4v acc3[2][4];
#pragma unroll
    for (int mt = 0; mt < 2; ++mt)
#pragma unroll
      for (int nt = 0; nt < 4; ++nt) {
        f4v a0 = {bias3[nt], bias3[nt], bias3[nt], bias3[nt]};
        acc3[mt][nt] = a0;
      }
#pragma unroll
    for (int ks = 0; ks < 2; ++ks)
#pragma unroll
      for (int nt = 0; nt < 4; ++nt) {
        s8v wf = *reinterpret_cast<const s8v*>(&sW3T[swzi(nt * 16 + cl, ks * 32 + q * 8, 64)]);
        acc3[0][nt] = __builtin_amdgcn_mfma_f32_16x16x32_bf16(af3[0][ks], wf, acc3[0][nt], 0, 0, 0);
        acc3[1][nt] = __builtin_amdgcn_mfma_f32_16x16x32_bf16(af3[1][ks], wf, acc3[1][nt], 0, 0, 0);
      }

    float m[4] = {0.0f, 0.0f, 0.0f, 0.0f};
#pragma unroll
    for (int nt = 0; nt < 4; ++nt)
#pragma unroll
      for (int mt = 0; mt < 2; ++mt)
#pragma unroll
        for (int i = 0; i < 4; ++i) m[nt] = fmaxf(m[nt], acc3[mt][nt][i]);
#pragma unroll
    for (int nt = 0; nt < 4; ++nt) {
      m[nt] = fmaxf(m[nt], __shfl_xor(m[nt], 16));
      m[nt] = fmaxf(m[nt], __shfl_xor(m[nt], 32));
    }
    float outv = (q == 0) ? m[0] : (q == 1) ? m[1] : (q == 2) ? m[2] : m[3];
    out[(size_t)v * HDIM + lane] = outv;
  }
}

extern "C" void kernel_launch(void* const* d_in, const int* in_sizes, int n_in,
                              void* d_out, int out_size, void* d_ws, size_t ws_size,
                              hipStream_t stream) {
  const float* x  = (const float*)d_in[0];
  const float* W1 = (const float*)d_in[2];
  const float* b1 = (const float*)d_in[3];
  const float* W2 = (const float*)d_in[4];
  const float* b2 = (const float*)d_in[5];
  const float* W3 = (const float*)d_in[6];
  const float* b3 = (const float*)d_in[7];
  float* out = (float*)d_out;
  int N = in_sizes[0] / FDIM;      // 32768
  int B = in_sizes[1] - 1;         // 16
  int V = N / B;                   // 2048

  char* ws = (char*)d_ws;
  float* sqbuf = (float*)ws;
  size_t off = (size_t)N * sizeof(float);
  int* idxbuf = (int*)(ws + off);
  off += (size_t)N * KNN * sizeof(int);
  off = (off + 255) & ~(size_t)255;
  float* Ubuf = (float*)(ws + off);
  off += (size_t)N * 64 * sizeof(float);
  unsigned short* Pbuf = (unsigned short*)(ws + off);

  sq_kernel<<<N / 4, 256, 0, stream>>>(x, sqbuf);
  uP_kernel<<<N / 128, 256, 0, stream>>>(x, W1, b1, Ubuf, Pbuf);
  knn_kernel<<<N / 32, 512, 0, stream>>>(x, sqbuf, idxbuf, V);
  mlp_kernel<<<N / 16, 256, 0, stream>>>(Ubuf, Pbuf, idxbuf, W2, b2, W3, b3, out, V);
}

// Round 6
// 196.155 us; speedup vs baseline: 1.2793x; 1.2793x over previous
//
#include <hip/hip_runtime.h>

#define KNN 30
#define FDIM 64
#define HDIM 64

typedef short s8v __attribute__((ext_vector_type(8)));   // 8 bf16 bit-patterns (4 VGPR)
typedef float f4v __attribute__((ext_vector_type(4)));   // MFMA accumulator
typedef unsigned long long u64;

// round-to-nearest-even f32 -> bf16 bits
static __device__ __forceinline__ unsigned short f2bf(float f) {
  unsigned int u = __builtin_bit_cast(unsigned int, f);
  u += 0x7fffu + ((u >> 16) & 1u);
  return (unsigned short)(u >> 16);
}
static __device__ __forceinline__ float bf2f(unsigned short h) {
  unsigned int u = ((unsigned int)h) << 16;
  return __builtin_bit_cast(float, u);
}

// f32 bits -> order-preserving u32 (asc float order == asc uint order)
static __device__ __forceinline__ unsigned int f2sort(float f) {
  unsigned int u = __builtin_bit_cast(unsigned int, f);
  unsigned int m = (unsigned int)(((int)u) >> 31) | 0x80000000u;
  return u ^ m;
}

// XOR swizzle (ushort-index space): byte ^= (row&7)<<4  <=>  idx ^= (row&7)<<3
static __device__ __forceinline__ int swzi(int row, int col, int roww) {
  return (row * roww + col) ^ ((row & 7) << 3);
}

static __device__ __forceinline__ void lds_fence() {
  asm volatile("s_waitcnt lgkmcnt(0)" ::: "memory");
  __builtin_amdgcn_sched_barrier(0);
}

static __device__ __forceinline__ s8v pack8(float4 a, float4 b) {
  s8v v;
  v[0] = (short)f2bf(a.x); v[1] = (short)f2bf(a.y);
  v[2] = (short)f2bf(a.z); v[3] = (short)f2bf(a.w);
  v[4] = (short)f2bf(b.x); v[5] = (short)f2bf(b.y);
  v[6] = (short)f2bf(b.z); v[7] = (short)f2bf(b.w);
  return v;
}

// ---------------- prep: xbf = bf16(x) (row-major [N][64]) and sq = |x|^2 (exact f32) ----
// 32 rows/block, 8 lanes per row.
__global__ __launch_bounds__(256) void prep_kernel(const float* __restrict__ x,
                                                   unsigned short* __restrict__ xbf,
                                                   float* __restrict__ sq) {
  int t = threadIdx.x;
  int r = blockIdx.x * 32 + (t >> 3);
  int sub = t & 7;
  const float* p = x + (size_t)r * FDIM + sub * 8;
  float4 a = *reinterpret_cast<const float4*>(p);
  float4 b = *reinterpret_cast<const float4*>(p + 4);
  *reinterpret_cast<s8v*>(xbf + (size_t)r * FDIM + sub * 8) = pack8(a, b);
  float s = a.x * a.x;
  s = fmaf(a.y, a.y, s); s = fmaf(a.z, a.z, s); s = fmaf(a.w, a.w, s);
  s = fmaf(b.x, b.x, s); s = fmaf(b.y, b.y, s); s = fmaf(b.z, b.z, s);
  s = fmaf(b.w, b.w, s);
  s += __shfl_xor(s, 1);
  s += __shfl_xor(s, 2);
  s += __shfl_xor(s, 4);
  if (sub == 0) sq[r] = s;
}

// ---------------- U/P precompute (layer-1 algebraic elimination) ----------------
__global__ __launch_bounds__(256) void uP_kernel(const float* __restrict__ x,
                                                 const float* __restrict__ W1,
                                                 const float* __restrict__ b1,
                                                 float* __restrict__ U,
                                                 unsigned short* __restrict__ P) {
  __shared__ __align__(16) unsigned short sWT[128 * 64];
  int t = threadIdx.x;
  for (int e = t; e < 64 * 64; e += 256) {
    int f = e >> 6, h = e & 63;
    float wa = W1[f * 64 + h];
    float wb = W1[(64 + f) * 64 + h];
    sWT[swzi(h, f, 64)] = f2bf(wa + wb);
    sWT[swzi(64 + h, f, 64)] = f2bf(wb);
  }
  __syncthreads();
  int wv = t >> 6, lane = t & 63;
  int q = lane >> 4, cl = lane & 15;
  int base = blockIdx.x * 128 + wv * 32;

  s8v af[2][2];
#pragma unroll
  for (int mt = 0; mt < 2; ++mt)
#pragma unroll
    for (int ks = 0; ks < 2; ++ks) {
      const float* px = x + (size_t)(base + mt * 16 + cl) * FDIM + ks * 32 + q * 8;
      float4 a = *reinterpret_cast<const float4*>(px);
      float4 b = *reinterpret_cast<const float4*>(px + 4);
      af[mt][ks] = pack8(a, b);
    }
  f4v acc[2][8];
#pragma unroll
  for (int nt = 0; nt < 8; ++nt) {
    float bb = (nt < 4) ? b1[nt * 16 + cl] : 0.0f;
    f4v a0 = {bb, bb, bb, bb};
    acc[0][nt] = a0;
    acc[1][nt] = a0;
  }
#pragma unroll
  for (int ks = 0; ks < 2; ++ks)
#pragma unroll
    for (int nt = 0; nt < 8; ++nt) {
      s8v wf = *reinterpret_cast<const s8v*>(&sWT[swzi(nt * 16 + cl, ks * 32 + q * 8, 64)]);
      acc[0][nt] = __builtin_amdgcn_mfma_f32_16x16x32_bf16(af[0][ks], wf, acc[0][nt], 0, 0, 0);
      acc[1][nt] = __builtin_amdgcn_mfma_f32_16x16x32_bf16(af[1][ks], wf, acc[1][nt], 0, 0, 0);
    }
#pragma unroll
  for (int mt = 0; mt < 2; ++mt)
#pragma unroll
    for (int nt = 0; nt < 8; ++nt)
#pragma unroll
      for (int i = 0; i < 4; ++i) {
        int row = base + mt * 16 + q * 4 + i;
        if (nt < 4) U[(size_t)row * 64 + nt * 16 + cl] = acc[mt][nt][i];
        else        P[(size_t)row * 64 + (nt - 4) * 16 + cl] = f2bf(acc[mt][nt][i]);
      }
}

// ---------------- dist16 v3: register-direct bf16 MFMA Gram -> u16 keys ----------------
// Fragments load straight from xbf (L2-resident) into VGPRs: no LDS staging, 1 barrier.
// key = clamp(round((sq[w] - 2*dot_bf16 + 256) * 64), 0, 65535).
__global__ __launch_bounds__(256) void dist16_kernel(const unsigned short* __restrict__ xbf,
                                                     const float* __restrict__ sq,
                                                     unsigned short* __restrict__ D16,
                                                     int R0, int V) {
  __shared__ __align__(16) unsigned short sK[128 * 128];  // 32KB key tile
  int t = threadIdx.x;
  int R = R0 + blockIdx.y * 128;
  int b = R / V;
  int w0 = blockIdx.x * 128;
  size_t bbase = (size_t)b * V;
  int wv = t >> 6, lane = t & 63;
  int q = lane >> 4, cl = lane & 15;
  int mq = wv >> 1, nq = wv & 1;  // 64x64 quadrant per wave

  s8v af[4][2], bfr[4][2];
#pragma unroll
  for (int mt = 0; mt < 4; ++mt)
#pragma unroll
    for (int ks = 0; ks < 2; ++ks) {
      af[mt][ks] = *reinterpret_cast<const s8v*>(
          xbf + (size_t)(R + mq * 64 + mt * 16 + cl) * FDIM + ks * 32 + q * 8);
      bfr[mt][ks] = *reinterpret_cast<const s8v*>(
          xbf + (bbase + (size_t)(w0 + nq * 64 + mt * 16 + cl)) * FDIM + ks * 32 + q * 8);
    }
  f4v acc[4][4];
#pragma unroll
  for (int mt = 0; mt < 4; ++mt)
#pragma unroll
    for (int nt = 0; nt < 4; ++nt) {
      f4v z = {0.0f, 0.0f, 0.0f, 0.0f};
      acc[mt][nt] = z;
    }
#pragma unroll
  for (int ks = 0; ks < 2; ++ks)
#pragma unroll
    for (int mt = 0; mt < 4; ++mt)
#pragma unroll
      for (int nt = 0; nt < 4; ++nt)
        acc[mt][nt] = __builtin_amdgcn_mfma_f32_16x16x32_bf16(af[mt][ks], bfr[nt][ks], acc[mt][nt], 0, 0, 0);
  float sql[4];
#pragma unroll
  for (int nt = 0; nt < 4; ++nt) sql[nt] = sq[bbase + w0 + nq * 64 + nt * 16 + cl];

  // keys -> LDS (row-swizzled)
#pragma unroll
  for (int mt = 0; mt < 4; ++mt)
#pragma unroll
    for (int nt = 0; nt < 4; ++nt)
#pragma unroll
      for (int i = 0; i < 4; ++i) {
        int rl = mq * 64 + mt * 16 + q * 4 + i;
        int cll = nq * 64 + nt * 16 + cl;
        float dk = fmaf(-128.0f, acc[mt][nt][i], fmaf(64.0f, sql[nt], 16384.0f));
        int ki = (int)(dk + 0.5f);
        ki = ki < 0 ? 0 : (ki > 65535 ? 65535 : ki);
        sK[rl * 128 + (cll ^ ((rl & 7) << 3))] = (unsigned short)ki;
      }
  __syncthreads();

  // coalesced store: 8-lane group writes one row's 256B contiguously
  {
    int sub = t & 7, rbase = t >> 3;
#pragma unroll
    for (int i = 0; i < 4; ++i) {
      int rr = i * 32 + rbase;
      int sw = (rr & 7) << 3;
      int c1 = (sub * 16) ^ sw;
      int c2 = (sub * 16 + 8) ^ sw;
      s8v k0 = *reinterpret_cast<const s8v*>(&sK[rr * 128 + c1]);
      s8v k1 = *reinterpret_cast<const s8v*>(&sK[rr * 128 + c2]);
      size_t gb = (size_t)(blockIdx.y * 128 + rr) * (size_t)V + w0 + sub * 16;
      *reinterpret_cast<s8v*>(D16 + gb) = k0;
      *reinterpret_cast<s8v*>(D16 + gb + 8) = k1;
    }
  }
}

// ---------------- topk16: approx-select (u16 keys + margin) + exact fp32 rescan ----------------
// Margin: |d_bf16 - d_fp32| <= E (=0.5, ~10 sigma). Exact-top-31 subset of
// {approx_key <= tau_key + 128E+2 = 66} where tau = rank-30 of 64 per-lane minima.
__global__ __launch_bounds__(256) void topk16_kernel(const unsigned short* __restrict__ D16,
                                                     const float* __restrict__ x,
                                                     const float* __restrict__ sq,
                                                     int* __restrict__ idxout,
                                                     int R0, int nrows, int V) {
  __shared__ unsigned int pool[4][128];
  __shared__ u64 pool2[4][128];
  __shared__ float sXv[4][64];
  int wave = threadIdx.x >> 6, lane = threadIdx.x & 63;
  int rowL = blockIdx.x * 4 + wave;
  if (rowL >= nrows) return;
  int R = R0 + rowL;
  int b = R / V;
  size_t bbase = (size_t)b * V;
  const unsigned short* row16 = D16 + (size_t)rowL * (size_t)V;

  // 32 combined keys per lane: (key16<<16)|w, w = s*512 + lane*8 + j
  unsigned int kv[32];
#pragma unroll
  for (int s = 0; s < 4; ++s) {
    s8v raw = *reinterpret_cast<const s8v*>(row16 + s * 512 + lane * 8);
#pragma unroll
    for (int j = 0; j < 8; ++j)
      kv[s * 8 + j] = ((unsigned int)(unsigned short)raw[j] << 16) | (unsigned int)(s * 512 + lane * 8 + j);
  }
  unsigned int mn = kv[0];
#pragma unroll
  for (int r = 1; r < 32; ++r) mn = min(mn, kv[r]);

  // bitonic-64 of lane minima -> tau (rank 30) bounds true rank-31 from above
  unsigned int srt = mn;
#pragma unroll
  for (int k = 2; k <= 64; k <<= 1) {
#pragma unroll
    for (int j = k >> 1; j > 0; j >>= 1) {
      unsigned int o = __shfl_xor(srt, j);
      bool keep_min = ((lane & k) == 0) == ((lane & j) == 0);
      bool less = srt < o;
      srt = (keep_min == less) ? srt : o;
    }
  }
  unsigned int tauk = (__shfl(srt, 30) >> 16) + 66;

  // compact candidates (key16 <= tauk) into pool
  int base = 0;
#pragma unroll
  for (int r = 0; r < 32; ++r) {
    bool pred = (kv[r] >> 16) <= tauk;
    u64 m = __ballot(pred);
    unsigned int off = __builtin_amdgcn_mbcnt_lo((unsigned int)m, 0u);
    off = __builtin_amdgcn_mbcnt_hi((unsigned int)(m >> 32), off);
    int slot = base + (int)off;
    if (pred && slot < 128) pool[wave][slot] = kv[r];
    base += (int)__popcll(m);
  }

  if (base <= 128) {
    lds_fence();
    // exact fp32 rescan: 8-lane groups, group g handles candidates it*8+g
    int g = lane >> 3, sub = lane & 7;
    const float* xvp = x + (size_t)R * FDIM + sub * 8;
    float4 xv0 = *reinterpret_cast<const float4*>(xvp);
    float4 xv1 = *reinterpret_cast<const float4*>(xvp + 4);
    float xv[8] = {xv0.x, xv0.y, xv0.z, xv0.w, xv1.x, xv1.y, xv1.z, xv1.w};
    int rounds = (base + 7) >> 3;
    for (int it = 0; it < rounds; ++it) {
      int c = it * 8 + g;
      unsigned int pk = pool[wave][c < base ? c : 0];
      int w = (int)(pk & 0xFFFFu);
      const float* xwp = x + (bbase + (unsigned int)w) * FDIM + sub * 8;
      float4 b0 = *reinterpret_cast<const float4*>(xwp);
      float4 b1 = *reinterpret_cast<const float4*>(xwp + 4);
      float dot = xv[0] * b0.x;
      dot = fmaf(xv[1], b0.y, dot); dot = fmaf(xv[2], b0.z, dot);
      dot = fmaf(xv[3], b0.w, dot); dot = fmaf(xv[4], b1.x, dot);
      dot = fmaf(xv[5], b1.y, dot); dot = fmaf(xv[6], b1.z, dot);
      dot = fmaf(xv[7], b1.w, dot);
      dot += __shfl_xor(dot, 1);
      dot += __shfl_xor(dot, 2);
      dot += __shfl_xor(dot, 4);
      float dx = fmaf(-2.0f, dot, sq[bbase + (unsigned int)w]);
      if (sub == 0 && c < base)
        pool2[wave][c] = ((u64)f2sort(dx) << 32) | (unsigned int)w;
    }
    lds_fence();
    u64 keyA = (lane < base) ? pool2[wave][lane] : ~0ULL;
    if (base <= 64) {
#pragma unroll
      for (int k = 2; k <= 64; k <<= 1) {
#pragma unroll
        for (int j = k >> 1; j > 0; j >>= 1) {
          u64 o = __shfl_xor(keyA, j);
          bool keep_min = ((lane & k) == 0) == ((lane & j) == 0);
          bool less = keyA < o;
          keyA = (keep_min == less) ? keyA : o;
        }
      }
      if (lane >= 1 && lane <= KNN)
        idxout[(size_t)R * KNN + (lane - 1)] = (int)(unsigned int)(keyA & 0xFFFFFFFFu);
    } else {
      u64 keyB = (64 + lane < base) ? pool2[wave][64 + lane] : ~0ULL;
#pragma unroll
      for (int k = 2; k <= 64; k <<= 1) {
#pragma unroll
        for (int j = k >> 1; j > 0; j >>= 1) {
          u64 oA = __shfl_xor(keyA, j);
          bool keep_min = ((lane & k) == 0) == ((lane & j) == 0);
          keyA = (keep_min == (keyA < oA)) ? keyA : oA;
          u64 oB = __shfl_xor(keyB, j);
          keyB = (keep_min == (keyB < oB)) ? keyB : oB;
        }
      }
      // merge: A asc + reverse(B asc) -> elementwise min is bitonic & holds smallest 64
      u64 keyBr = __shfl(keyB, 63 - lane);
      u64 mnk = keyA < keyBr ? keyA : keyBr;
#pragma unroll
      for (int j = 32; j > 0; j >>= 1) {
        u64 o = __shfl_xor(mnk, j);
        bool keep_min = (lane & j) == 0;
        mnk = (keep_min == (mnk < o)) ? mnk : o;
      }
      if (lane >= 1 && lane <= KNN)
        idxout[(size_t)R * KNN + (lane - 1)] = (int)(unsigned int)(mnk & 0xFFFFFFFFu);
    }
  } else {
    // exhaustive exact fallback (pathological clustering only): full row in fp32
    sXv[wave][lane] = x[(size_t)R * FDIM + lane];
    lds_fence();
    unsigned int sve[32];
#pragma unroll 1
    for (int s = 0; s < 4; ++s)
#pragma unroll 1
      for (int j = 0; j < 8; ++j) {
        int w = s * 512 + lane * 8 + j;
        const float* xw = x + (bbase + (unsigned int)w) * FDIM;
        float dot = 0.0f;
        for (int f = 0; f < 64; ++f) dot = fmaf(sXv[wave][f], xw[f], dot);
        sve[s * 8 + j] = f2sort(fmaf(-2.0f, dot, sq[bbase + (unsigned int)w]));
      }
    unsigned int removed = 0;
    for (int it = 0; it < KNN + 1; ++it) {
      u64 m = ~0ULL;
#pragma unroll
      for (int r = 0; r < 32; ++r) {
        u64 key = ((u64)sve[r] << 32) | (unsigned int)((r >> 3) * 512 + lane * 8 + (r & 7));
        bool alive = ((removed >> r) & 1u) == 0u;
        if (alive && key < m) m = key;
      }
      u64 gk = m;
#pragma unroll
      for (int off = 32; off; off >>= 1) {
        u64 o = __shfl_xor(gk, off);
        gk = (o < gk) ? o : gk;
      }
      if (it > 0 && lane == 0) idxout[(size_t)R * KNN + (it - 1)] = (int)(unsigned int)(gk & 0xFFFFFFFFu);
#pragma unroll
      for (int r = 0; r < 32; ++r) {
        u64 key = ((u64)sve[r] << 32) | (unsigned int)((r >> 3) * 512 + lane * 8 + (r & 7));
        if (key == gk) removed |= (1u << r);
      }
    }
  }
}

// ---------------- fused layers 2,3 + max aggregation ----------------
__global__ __launch_bounds__(256) void mlp_kernel(const float* __restrict__ U,
                                                  const unsigned short* __restrict__ P,
                                                  const int* __restrict__ idx,
                                                  const float* __restrict__ W2,
                                                  const float* __restrict__ b2,
                                                  const float* __restrict__ W3,
                                                  const float* __restrict__ b3,
                                                  float* __restrict__ out, int V) {
  __shared__ __align__(16) unsigned short sW2T[HDIM * HDIM];
  __shared__ __align__(16) unsigned short sW3T[HDIM * HDIM];
  __shared__ __align__(16) unsigned short sScr[4][2048];
  int t = threadIdx.x;
  for (int e = t; e < HDIM * HDIM; e += 256) {
    int i = e >> 6, j = e & 63;
    sW2T[swzi(j, i, 64)] = f2bf(W2[e]);
    int s = (i & 15) * 4 + (i >> 4);
    sW3T[swzi(j, s, 64)] = f2bf(W3[e]);
  }
  __syncthreads();

  int wv = t >> 6, lane = t & 63;
  int q = lane >> 4, cl = lane & 15;
  int g = lane >> 3, sub = lane & 7;
  unsigned short* scr = &sScr[wv][0];
  float bias2[4], bias3[4];
#pragma unroll
  for (int nt = 0; nt < 4; ++nt) {
    bias2[nt] = b2[nt * 16 + cl];
    bias3[nt] = b3[nt * 16 + cl];
  }

  for (int vi = 0; vi < 4; ++vi) {
    int v = blockIdx.x * 16 + wv * 4 + vi;
    int b = v / V;
    size_t bbase = (size_t)b * V;
    int myidx = (lane < KNN) ? idx[(size_t)v * KNN + lane] : 0;
    const float* up = U + (size_t)v * 64 + sub * 8;
    float4 u0 = *reinterpret_cast<const float4*>(up);
    float4 u1 = *reinterpret_cast<const float4*>(up + 4);
    float uu[8] = {u0.x, u0.y, u0.z, u0.w, u1.x, u1.y, u1.z, u1.w};

#pragma unroll
    for (int it = 0; it < 4; ++it) {
      int r = it * 8 + g;
      int kk = (r < KNN) ? r : (KNN - 1);
      int nb = __shfl(myidx, kk);
      const unsigned short* pp = P + (bbase + (unsigned int)nb) * 64 + sub * 8;
      s8v p8 = *reinterpret_cast<const s8v*>(pp);
      s8v hv;
#pragma unroll
      for (int j = 0; j < 8; ++j) {
        float f = uu[j] - bf2f((unsigned short)p8[j]);
        hv[j] = (short)f2bf(fmaxf(f, 0.0f));
      }
      *reinterpret_cast<s8v*>(&scr[swzi(r, sub * 8, 64)]) = hv;
    }
    lds_fence();

    s8v af2[2][2];
#pragma unroll
    for (int mt = 0; mt < 2; ++mt)
#pragma unroll
      for (int ks = 0; ks < 2; ++ks)
        af2[mt][ks] = *reinterpret_cast<const s8v*>(&scr[swzi(mt * 16 + cl, ks * 32 + q * 8, 64)]);
    f4v acc2[2][4];
#pragma unroll
    for (int mt = 0; mt < 2; ++mt)
#pragma unroll
      for (int nt = 0; nt < 4; ++nt) {
        f4v a0 = {bias2[nt], bias2[nt], bias2[nt], bias2[nt]};
        acc2[mt][nt] = a0;
      }
#pragma unroll
    for (int ks = 0; ks < 2; ++ks)
#pragma unroll
      for (int nt = 0; nt < 4; ++nt) {
        s8v wf = *reinterpret_cast<const s8v*>(&sW2T[swzi(nt * 16 + cl, ks * 32 + q * 8, 64)]);
        acc2[0][nt] = __builtin_amdgcn_mfma_f32_16x16x32_bf16(af2[0][ks], wf, acc2[0][nt], 0, 0, 0);
        acc2[1][nt] = __builtin_amdgcn_mfma_f32_16x16x32_bf16(af2[1][ks], wf, acc2[1][nt], 0, 0, 0);
      }
    lds_fence();
#pragma unroll
    for (int mt = 0; mt < 2; ++mt)
#pragma unroll
      for (int i = 0; i < 4; ++i) {
        int m = mt * 16 + q * 4 + i;
        u64 pk = 0;
#pragma unroll
        for (int nt = 0; nt < 4; ++nt) {
          u64 hb = f2bf(fmaxf(acc2[mt][nt][i], 0.0f));
          pk |= hb << (16 * nt);
        }
        *reinterpret_cast<u64*>(&scr[swzi(m, cl * 4, 64)]) = pk;
      }
    lds_fence();

    s8v af3[2][2];
#pragma unroll
    for (int mt = 0; mt < 2; ++mt)
#pragma unroll
      for (int ks = 0; ks < 2; ++ks)
        af3[mt][ks] = *reinterpret_cast<const s8v*>(&scr[swzi(mt * 16 + cl, ks * 32 + q * 8, 64)]);
    f4v acc3[2][4];
#pragma unroll
    for (int mt = 0; mt < 2; ++mt)
#pragma unroll
      for (int nt = 0; nt < 4; ++nt) {
        f4v a0 = {bias3[nt], bias3[nt], bias3[nt], bias3[nt]};
        acc3[mt][nt] = a0;
      }
#pragma unroll
    for (int ks = 0; ks < 2; ++ks)
#pragma unroll
      for (int nt = 0; nt < 4; ++nt) {
        s8v wf = *reinterpret_cast<const s8v*>(&sW3T[swzi(nt * 16 + cl, ks * 32 + q * 8, 64)]);
        acc3[0][nt] = __builtin_amdgcn_mfma_f32_16x16x32_bf16(af3[0][ks], wf, acc3[0][nt], 0, 0, 0);
        acc3[1][nt] = __builtin_amdgcn_mfma_f32_16x16x32_bf16(af3[1][ks], wf, acc3[1][nt], 0, 0, 0);
      }

    float m[4] = {0.0f, 0.0f, 0.0f, 0.0f};
#pragma unroll
    for (int nt = 0; nt < 4; ++nt)
#pragma unroll
      for (int mt = 0; mt < 2; ++mt)
#pragma unroll
        for (int i = 0; i < 4; ++i) m[nt] = fmaxf(m[nt], acc3[mt][nt][i]);
#pragma unroll
    for (int nt = 0; nt < 4; ++nt) {
      m[nt] = fmaxf(m[nt], __shfl_xor(m[nt], 16));
      m[nt] = fmaxf(m[nt], __shfl_xor(m[nt], 32));
    }
    float outv = (q == 0) ? m[0] : (q == 1) ? m[1] : (q == 2) ? m[2] : m[3];
    out[(size_t)v * HDIM + lane] = outv;
  }
}

extern "C" void kernel_launch(void* const* d_in, const int* in_sizes, int n_in,
                              void* d_out, int out_size, void* d_ws, size_t ws_size,
                              hipStream_t stream) {
  const float* x  = (const float*)d_in[0];
  const float* W1 = (const float*)d_in[2];
  const float* b1 = (const float*)d_in[3];
  const float* W2 = (const float*)d_in[4];
  const float* b2 = (const float*)d_in[5];
  const float* W3 = (const float*)d_in[6];
  const float* b3 = (const float*)d_in[7];
  float* out = (float*)d_out;
  int N = in_sizes[0] / FDIM;      // 32768
  int B = in_sizes[1] - 1;         // 16
  int V = N / B;                   // 2048

  char* ws = (char*)d_ws;
  float* sqbuf = (float*)ws;
  size_t off = (size_t)N * sizeof(float);
  int* idxbuf = (int*)(ws + off);
  off += (size_t)N * KNN * sizeof(int);
  off = (off + 255) & ~(size_t)255;
  float* Ubuf = (float*)(ws + off);
  off += (size_t)N * 64 * sizeof(float);
  unsigned short* Pbuf = (unsigned short*)(ws + off);
  off += (size_t)N * 64 * sizeof(unsigned short);
  off = (off + 255) & ~(size_t)255;
  unsigned short* xbfbuf = (unsigned short*)(ws + off);
  off += (size_t)N * 64 * sizeof(unsigned short);
  off = (off + 255) & ~(size_t)255;
  unsigned short* D16buf = (unsigned short*)(ws + off);
  size_t dcap = (ws_size > off) ? (ws_size - off) : 0;
  long long capRows = (long long)(dcap / ((size_t)V * sizeof(unsigned short)));
  capRows &= ~127LL;
  if (capRows > N) capRows = N;
  if (capRows < 128) capRows = 128;  // requires sufficient ws_size

  prep_kernel<<<N / 32, 256, 0, stream>>>(x, xbfbuf, sqbuf);
  uP_kernel<<<N / 128, 256, 0, stream>>>(x, W1, b1, Ubuf, Pbuf);
  for (int R0 = 0; R0 < N; R0 += (int)capRows) {
    int nr = N - R0;
    if (nr > capRows) nr = (int)capRows;
    dim3 g(V / 128, nr / 128);
    dist16_kernel<<<g, 256, 0, stream>>>(xbfbuf, sqbuf, D16buf, R0, V);
    topk16_kernel<<<nr / 4, 256, 0, stream>>>(D16buf, x, sqbuf, idxbuf, R0, nr, V);
  }
  mlp_kernel<<<N / 16, 256, 0, stream>>>(Ubuf, Pbuf, idxbuf, W2, b2, W3, b3, out, V);
}